// Round 8
// baseline (156.773 us; speedup 1.0000x reference)
//
#include <hip/hip_runtime.h>

#define NRBF 20
#define FOUT 16
#define NA 768
#define NB 4
#define NT 48            // m-tiles per row (768/16)
#define NWAVES 12288     // 3072 blocks x 4 waves

// Round-11: GLOBAL write-window scheduling (the fill's temporal shape).
//
// Falsified so far: compute amount (R6), store instr width (R7), full-line
// coverage (R8/R10 clean), chain depth (R9 small), occupancy (R4). Kernel
// pinned at ~62us vs 24us write floor while the harness fill hits 6.5 TB/s.
// Last structural difference vs the fill: the fill's grid-stride loop keeps
// ALL outstanding writes chip-wide inside one ~MB address window sweeping
// linearly; ours had 2048 resident blocks streaming private 48KB regions ->
// instantaneous footprint ~100MB -> HBM row-buffer thrash.
//
// New schedule: global wave W = blockIdx.x*4 + wave; step i=0..11 writes tile
// tile_idx = i*12288 + W  -> at any instant the GPU writes one contiguous
// 12MB sweeping window. Decode (exact): t = W%48 (FIXED m-tile per wave ->
// its 16 m-coords preload once per batch), r = W/48, b = i/3,
// n = (i%3)*256 + r (wave-uniform -> broadcast loads, L2-hot).
// Identity check: ((b*768+n)*48 + t)*256 = (b*3+i%3)*12288*256 + (r*48+t)*256
// = tile_idx*256 floats = tile base. Bijective over [0, 151MB).
//
// Everything value-producing is bit-identical to R10 (validated): gauge
// k=(l>>4)*8+j fragments, W-side zero-pad, swapped-operand MFMA, raw v_sqrt,
// telescoped recurrence, bias as C-in, 4x ds_bpermute dense-store permute
// (lane l <- lane ((l&3)<<4)|(l>>2), stores dwords 4l..4l+3 of the 1KB tile).
// Only the wave->tile assignment (a schedule permutation) changed.

typedef _Float16 f16x8 __attribute__((ext_vector_type(8)));
typedef float    f32x4 __attribute__((ext_vector_type(4)));

__global__ __launch_bounds__(256, 6) void cfconv_kernel(
    const float* __restrict__ coords,  // [NB, NA, 3] fp32
    const float* __restrict__ Ww,      // [FOUT, NRBF] fp32
    const float* __restrict__ Wb,      // [FOUT] fp32
    float* __restrict__ out)           // [NB, NA, NA, FOUT] fp32
{
    const int tid = threadIdx.x;
    const int w   = tid >> 6;          // wave in block
    const int l   = tid & 63;
    const int mi  = l & 15;            // m sub-index (B col / D col)
    const int g   = l >> 4;            // k-group; lane's D rows f = 4g+0..3

    const int W = blockIdx.x * 4 + w;  // global wave id 0..12287
    const int r = W / NT;              // row-group 0..255
    const int t = W % NT;              // this wave's FIXED m-tile

    // A fragment = W[f = mi][k = 8g+j], zero-padded k >= 20 (L2-hot loads)
    f16x8 afrag;
    #pragma unroll
    for (int j = 0; j < 8; ++j) {
        const int k = g * 8 + j;
        afrag[j] = (k < NRBF) ? (_Float16)Ww[mi * NRBF + k] : (_Float16)0.0f;
    }
    // C-in rows are f = 4g+rr -> bias per reg
    const f32x4 cinit = { Wb[4*g+0], Wb[4*g+1], Wb[4*g+2], Wb[4*g+3] };

    const float mu0  = 0.1f * (8 * g);          // segment-start mu
    const float tcst = 0.2f * (8 * g) + 0.1f;   // t_{k0+1} exponent offset
    const float u    = 0.81873075308f;          // e^{-0.2}

    // dense-store permute source lane (validated R8/R10)
    const int srcLane = ((l & 3) << 4) | (l >> 2);
    float* obase = out + (size_t)l * 4;         // lane slot within each tile

    #pragma unroll
    for (int b = 0; b < NB; ++b) {
        const float* cb = coords + (size_t)b * NA * 3;
        // this wave's 16 m-coordinates for batch b (per-lane, L2-hot)
        const int m  = t * 16 + mi;
        const float xm = cb[m*3+0], ym = cb[m*3+1], zm = cb[m*3+2];

        // phase 1: the 3 row-coord triples + 3 independent distance chains
        float d0, d1, d2;
        {
            const int n0 = 0*256 + r, n1 = 1*256 + r, n2 = 2*256 + r;
            const float x0 = cb[n0*3+0], y0 = cb[n0*3+1], z0 = cb[n0*3+2];
            const float x1 = cb[n1*3+0], y1 = cb[n1*3+1], z1 = cb[n1*3+2];
            const float x2 = cb[n2*3+0], y2 = cb[n2*3+1], z2 = cb[n2*3+2];
            const float ax = x0-xm, ay = y0-ym, az = z0-zm;
            const float bx = x1-xm, by = y1-ym, bz = z1-zm;
            const float cx = x2-xm, cy = y2-ym, cz = z2-zm;
            d0 = __builtin_amdgcn_sqrtf(fmaf(ax,ax,fmaf(ay,ay,az*az)));
            d1 = __builtin_amdgcn_sqrtf(fmaf(bx,bx,fmaf(by,by,bz*bz)));
            d2 = __builtin_amdgcn_sqrtf(fmaf(cx,cx,fmaf(cy,cy,cz*cz)));
        }
        const float dv[3] = { d0, d1, d2 };

        // phase 2: 3 independent {exp, recurrence, MFMA, permute, store}
        #pragma unroll
        for (int ii = 0; ii < 3; ++ii) {
            const float d  = dv[ii];
            const float dd = d - mu0;
            float rr = __expf(-10.0f * dd * dd);    // r_{k0}
            float q  = __expf(2.0f * d - tcst);     // ratio t_{k0+1}

            f16x8 bfrag;                            // B[k = 8g+j][m = mi]
            bfrag[0] = (_Float16)rr;
            #pragma unroll
            for (int j = 1; j < 8; ++j) {
                rr *= q;                            // r_{k0+j}
                q  *= u;
                bfrag[j] = (_Float16)rr;
            }

            f32x4 acc =                             // D = W * RBF^T + bias
                __builtin_amdgcn_mfma_f32_16x16x32_f16(afrag, bfrag, cinit, 0, 0, 0);

            // permute D to lane-dense layout (only lgkm ops in the kernel)
            f32x4 sv;
            sv[0] = __shfl(acc[0], srcLane);
            sv[1] = __shfl(acc[1], srcLane);
            sv[2] = __shfl(acc[2], srcLane);
            sv[3] = __shfl(acc[3], srcLane);

            // sweeping-window schedule: step i = b*3+ii writes the contiguous
            // chip-wide 12MB window [i*12MB, (i+1)*12MB)
            const size_t tile_idx = (size_t)(b * 3 + ii) * NWAVES + W;
            *reinterpret_cast<f32x4*>(obase + tile_idx * 256) = sv;
        }
    }
}

extern "C" void kernel_launch(void* const* d_in, const int* in_sizes, int n_in,
                              void* d_out, int out_size, void* d_ws, size_t ws_size,
                              hipStream_t stream) {
    const float* coords = (const float*)d_in[0];
    const float* Ww     = (const float*)d_in[1];
    const float* Wb     = (const float*)d_in[2];
    float* out          = (float*)d_out;

    dim3 grid(NWAVES / 4);   // 3072 blocks x 256 threads = 12288 waves
    cfconv_kernel<<<grid, 256, 0, stream>>>(coords, Ww, Wb, out);
}